// Round 3
// baseline (168.918 us; speedup 1.0000x reference)
//
#include <hip/hip_runtime.h>
#include <stdint.h>
#include <math.h>

typedef unsigned int u32;
typedef unsigned long long u64;

#define NN_ 28800
#define MM_ 64
#define BB_ 16
#define XROW_ 25
#define POS_CAP_ 128u
#define BATCH_ 256u

#define R0_BLKS 113               // ceil(28800/256)
#define R0_TOT (R0_BLKS*BB_)      // 1808 anchor-major blocks
#define R1_TOT (BB_*MM_)          // 1024 gt-major blocks
#define GRID_IOU (R0_TOT + R1_TOT)

#define ZBYTES (128 + 128 + 524288)   // counts + listcnt + hist
#define ZWORDS (ZBYTES/4)             // 131136

struct Keys { u32 k[BB_][4]; };

// ---------------- threefry2x32 (JAX-exact), host+device ----------------
__host__ __device__ __forceinline__ u32 rotl32(u32 v, u32 r){ return (v<<r)|(v>>(32u-r)); }

__host__ __device__ __forceinline__ void tf2x32(u32 k0, u32 k1, u32 x0, u32 x1, u32& y0, u32& y1){
  u32 ks2 = k0 ^ k1 ^ 0x1BD11BDAu;
  x0 += k0; x1 += k1;
#define TFR(r) { x0 += x1; x1 = rotl32(x1,(r)); x1 ^= x0; }
  TFR(13) TFR(15) TFR(26) TFR(6)   x0 += k1;  x1 += ks2 + 1u;
  TFR(17) TFR(29) TFR(16) TFR(24)  x0 += ks2; x1 += k0  + 2u;
  TFR(13) TFR(15) TFR(26) TFR(6)   x0 += k0;  x1 += k1  + 3u;
  TFR(17) TFR(29) TFR(16) TFR(24)  x0 += k1;  x1 += ks2 + 4u;
  TFR(13) TFR(15) TFR(26) TFR(6)   x0 += ks2; x1 += k0  + 5u;
#undef TFR
  y0 = x0; y1 = x1;
}

// ---------------- anchors: pure-float, bit-exact vs numpy ----------------
// float(s_d*sqrt_d(r)) == s_f * float(sqrt_d(r)) because s is a power of 2
// (pow2 scaling commutes with rounding). SQH/SQ2 round to 0x3F3504F3/0x3FB504F3.
__device__ __forceinline__ void anchor_from(int a, int cell,
                                            float& ox1, float& oy1, float& ox2, float& oy2){
  #pragma clang fp contract(off)
  int w = cell & 63;
  int h = cell >> 6;
  int p = (a >= 6) ? 2 : ((a >= 3) ? 1 : 0);
  int q = a - p*3;
  float sf = (p==0) ? 128.0f : ((p==1) ? 256.0f : 512.0f);
  const float SQH = 0.70710678118654752440f;
  const float SQ2 = 1.41421356237309514547f;
  float cw = (q==0) ? SQH : ((q==1) ? 1.0f : SQ2);
  float ch = (q==0) ? SQ2 : ((q==1) ? 1.0f : SQH);
  float hx = (sf*cw) * 0.5f;
  float hy = (sf*ch) * 0.5f;
  float cx = ((float)w + 0.5f) * 16.0f;
  float cy = ((float)h + 0.5f) * 16.0f;
  float X1 = (cx - hx) / 1024.0f;
  float Y1 = (cy - hy) / 800.0f;
  float X2 = (cx + hx) / 1024.0f;
  float Y2 = (cy + hy) / 800.0f;
  bool valid = (X1 > 0.0f) && (Y1 > 0.0f) && (X2 < 1.0f) && (Y2 < 1.0f);
  ox1 = valid ? X1 : 0.0f;
  oy1 = valid ? Y1 : 0.0f;
  ox2 = valid ? X2 : 0.0f;
  oy2 = valid ? Y2 : 0.0f;
}

// ---------------- K1 fused: anchor-major (mcode/midx) + gt-major (bestkey) + ws zero ----------------
__global__ __launch_bounds__(256) void k_iou(const float* __restrict__ x,
                                             unsigned char* __restrict__ mcode,
                                             unsigned char* __restrict__ midx,
                                             u64* __restrict__ bestkey,
                                             u32* __restrict__ zbuf){
  #pragma clang fp contract(off)
  int tid = threadIdx.x;
  int bid = blockIdx.x;
  { int gid = bid*256 + tid; if (gid < ZWORDS) zbuf[gid] = 0u; }

  if (bid < R0_TOT){
    // ---- anchor-major: matched_iou code + argmax over gts ----
    int b   = bid / R0_BLKS;
    int blk = bid % R0_BLKS;
    __shared__ float g[MM_][4];
    g[tid>>2][tid&3] = x[b*MM_*XROW_ + (tid>>2)*XROW_ + 21 + (tid&3)];
    __syncthreads();
    int i = blk*256 + tid;
    if (i >= NN_) return;
    int a = i % 9, cell = i / 9;
    float ax1,ay1,ax2,ay2;
    anchor_from(a, cell, ax1,ay1,ax2,ay2);
    bool av = (ax2 > 0.0f);
    if (__ballot(av) == 0ull){
      mcode[b*NN_+i] = 2;   // miou = 0: not pos, is neg
      midx[b*NN_+i] = 0;
      return;
    }
    float area_a = (ax2-ax1)*(ay2-ay1);
    float best = -1.0f; int bj = 0;
    for (int j = 0; j < MM_; ++j){
      float g0=g[j][0], g1=g[j][1], g2=g[j][2], g3=g[j][3];
      float ix1 = fmaxf(ax1,g0), iy1 = fmaxf(ay1,g1);
      float ix2 = fminf(ax2,g2), iy2 = fminf(ay2,g3);
      float iw = fmaxf(ix2-ix1, 0.0f), ih = fmaxf(iy2-iy1, 0.0f);
      float inter = iw*ih;
      float area_g = (g2-g0)*(g3-g1);
      float den = area_a + area_g;   // exact reference op order, no FMA
      den = den - inter;
      den = den + 1e-7f;
      float iou = inter / den;
      if (iou > best){ best = iou; bj = j; }   // first-max semantics
    }
    unsigned char code = (unsigned char)((best > 0.7f ? 1 : 0) | (best < 0.3f ? 2 : 0));
    mcode[b*NN_+i] = code;
    midx[b*NN_+i] = (unsigned char)bj;
  } else {
    // ---- gt-major: per-(b,j) argmax over all anchors ----
    int r = bid - R0_TOT;
    int b = r >> 6;
    int j = r & 63;
    const float* gp = x + b*MM_*XROW_ + j*XROW_ + 21;
    float g0 = gp[0], g1 = gp[1], g2 = gp[2], g3 = gp[3];
    float area_g = (g2-g0)*(g3-g1);
    u64 bk = 0;
    int a = tid % 9, cell = tid / 9;
    for (int i = tid; i < NN_; i += 256){
      float ax1,ay1,ax2,ay2;
      anchor_from(a, cell, ax1,ay1,ax2,ay2);
      float area_a = (ax2-ax1)*(ay2-ay1);
      float ix1 = fmaxf(ax1,g0), iy1 = fmaxf(ay1,g1);
      float ix2 = fminf(ax2,g2), iy2 = fminf(ay2,g3);
      float iw = fmaxf(ix2-ix1, 0.0f), ih = fmaxf(iy2-iy1, 0.0f);
      float inter = iw*ih;
      float den = area_a + area_g;
      den = den - inter;
      den = den + 1e-7f;
      float iou = inter / den;
      u32 ib = __float_as_uint(iou);
      if (ib){
        u64 key = ((u64)ib << 32) | (u64)(0xFFFFFFFFu - (u32)i);
        if (key > bk) bk = key;
      }
      a += 4; cell += 28; if (a >= 9){ a -= 9; cell += 1; }   // i += 256 == 9*28+4
    }
    __shared__ u64 red[256];
    red[tid] = bk; __syncthreads();
    #pragma unroll
    for (int s = 128; s >= 1; s >>= 1){
      if (tid < s){ u64 o = red[tid+s]; if (o > red[tid]) red[tid] = o; }
      __syncthreads();
    }
    if (tid == 0) bestkey[b*MM_ + j] = red[0];
  }
}

// ---------------- K2: PRNG + candidates + counts + hist (forced from bestkey in-block) ----------------
__global__ __launch_bounds__(256) void k_rand(const unsigned char* __restrict__ mcode,
                                              const u64* __restrict__ bestkey,
                                              Keys keys,
                                              u32* __restrict__ rpv, u32* __restrict__ rnv,
                                              u32* __restrict__ counts, u32* __restrict__ hist){
  int b = blockIdx.y, tid = threadIdx.x;
  int i0 = blockIdx.x*256;
  int i = i0 + tid;
  __shared__ u32 fmask[8];
  __shared__ u32 sc[2];
  if (tid < 8) fmask[tid] = 0;
  if (tid < 2) sc[tid] = 0;
  __syncthreads();
  if (tid < MM_){
    u64 key = bestkey[b*MM_ + tid];
    if ((u32)(key >> 32) != 0u){
      u32 fi = 0xFFFFFFFFu - (u32)key;
      u32 rel = fi - (u32)i0;
      if (rel < 256u) atomicOr(&fmask[rel>>5], 1u << (rel & 31));
    }
  }
  __syncthreads();
  bool pc = false, nc = false;
  if (i < NN_){
    u32 a0,a1,c0,c1;
    tf2x32(keys.k[b][0], keys.k[b][1], 0u, (u32)i, a0,a1);
    tf2x32(keys.k[b][2], keys.k[b][3], 0u, (u32)i, c0,c1);
    u32 code = mcode[b*NN_+i];
    bool fb = (fmask[tid>>5] >> (tid & 31)) & 1u;
    pc = (code & 1u) || fb;
    nc = (code >> 1) & 1u;
    u32 ph = (a0^a1) >> 9, nh = (c0^c1) >> 9;   // 23-bit rank keys
    rpv[b*NN_+i] = pc ? ph + 1u : 0u;
    rnv[b*NN_+i] = nc ? nh + 1u : 0u;
    if (pc) atomicAdd(&hist[((b*2+0)<<12) + (ph>>11)], 1u);
    if (nc) atomicAdd(&hist[((b*2+1)<<12) + (nh>>11)], 1u);
  }
  u64 bp = __ballot(pc), bn = __ballot(nc);
  if ((tid & 63) == 0){
    if (bp) atomicAdd(&sc[0], (u32)__popcll(bp));
    if (bn) atomicAdd(&sc[1], (u32)__popcll(bn));
  }
  __syncthreads();
  if (tid == 0){
    if (sc[0]) atomicAdd(&counts[b*2+0], sc[0]);
    if (sc[1]) atomicAdd(&counts[b*2+1], sc[1]);
  }
}

// ---------------- K3: find threshold bin from hist + collect bin members (8-way sliced) ----------------
__global__ __launch_bounds__(256) void k_collect(const u32* __restrict__ rpv,
                                                 const u32* __restrict__ rnv,
                                                 const u32* __restrict__ counts,
                                                 const u32* __restrict__ hist,
                                                 u64* __restrict__ list,
                                                 u32* __restrict__ listcnt,
                                                 u32* __restrict__ binfo){
  int slice = blockIdx.x;        // 0..7
  int b = blockIdx.y, cls = blockIdx.z;
  int tid = threadIdx.x;
  u32 posc = counts[b*2+0], negc = counts[b*2+1];
  u32 npos = min(posc, POS_CAP_);
  u32 K   = cls ? (BATCH_ - npos) : npos;
  u32 cnt = cls ? negc : posc;
  if (cnt <= K) return;          // uniform exit: no selection needed

  const u32* H = hist + ((b*2+cls) << 12);
  __shared__ u32 ts[256], ss[256];
  __shared__ u32 bc[2];
  u32 s = 0;
  #pragma unroll
  for (int q = 0; q < 16; ++q) s += H[tid*16 + q];
  ts[tid] = s; ss[tid] = s;
  __syncthreads();
  // inclusive suffix scan over 256 chunks
  for (int off = 1; off < 256; off <<= 1){
    u32 vv = (tid + off < 256) ? ss[tid + off] : 0u;
    __syncthreads();
    ss[tid] += vv;
    __syncthreads();
  }
  u32 excl = (tid < 255) ? ss[tid+1] : 0u;   // count in strictly-higher chunks
  if (excl < K && excl + ts[tid] >= K){
    u32 acc = excl;
    for (int q = 15; q >= 0; --q){
      u32 h = H[tid*16 + q];
      if (acc + h >= K){ bc[0] = (u32)(tid*16 + q); bc[1] = K - acc; break; }
      acc += h;
    }
  }
  __syncthreads();
  u32 B = bc[0];
  if (slice == 0 && tid == 0) binfo[b*2+cls] = bc[1];   // Kp

  const u32* v = (cls ? rnv : rpv) + (size_t)b*NN_;
  int ibase = slice * 3600;                  // 28800 = 8*3600
  for (int i = ibase + tid; i < ibase + 3600; i += 256){
    u32 xv = v[i];
    if (xv && ((xv - 1u) >> 11) == B){
      u32 p = atomicAdd(&listcnt[b*2+cls], 1u);
      if (p < 512u) list[(size_t)(b*2+cls)*512 + p] = ((u64)xv << 32) | (u32)i;
    }
  }
}

// ---------------- K4: exact (vstar, cut) from the tiny bin list ----------------
__global__ __launch_bounds__(64) void k_decide(const u32* __restrict__ counts,
                                               const u32* __restrict__ listcnt,
                                               const u32* __restrict__ binfo,
                                               const u64* __restrict__ list,
                                               u32* __restrict__ selp){
  int id = blockIdx.x;           // b*2+cls
  int b = id >> 1, cls = id & 1;
  int lane = threadIdx.x;
  u32 posc = counts[b*2+0], negc = counts[b*2+1];
  u32 npos = min(posc, POS_CAP_);
  u32 K   = cls ? (BATCH_ - npos) : npos;
  u32 cnt = cls ? negc : posc;
  if (cnt <= K){
    if (lane == 0){ selp[id*2+0] = 0u; selp[id*2+1] = 0xFFFFFFFFu; }
    return;
  }
  u32 Kp = binfo[id];
  u32 n = min(listcnt[id], 512u);
  __shared__ u64 L[512];
  for (u32 e = lane; e < n; e += 64) L[e] = list[(size_t)id*512 + e];
  __syncthreads();
  for (u32 e = lane; e < n; e += 64){
    u64 me = L[e]; u32 mv = (u32)(me >> 32), mi = (u32)me;
    u32 r = 0;
    for (u32 t = 0; t < n; ++t){
      u64 o = L[t]; u32 ov = (u32)(o >> 32), oi = (u32)o;
      r += (ov > mv) || (ov == mv && oi < mi);
    }
    if (r == Kp - 1u){ selp[id*2+0] = mv; selp[id*2+1] = mi; }
  }
}

// ---------------- K5: final cls + encoded offsets ----------------
__global__ __launch_bounds__(256) void k_out(const float* __restrict__ x,
                                             const unsigned char* __restrict__ midx,
                                             const u32* __restrict__ rpv,
                                             const u32* __restrict__ rnv,
                                             const u32* __restrict__ selp,
                                             float* __restrict__ out){
  #pragma clang fp contract(off)
  int b = blockIdx.y, tid = threadIdx.x;
  __shared__ float g[MM_][4];
  g[tid>>2][tid&3] = x[b*MM_*XROW_ + (tid>>2)*XROW_ + 21 + (tid&3)];
  __syncthreads();
  int i = blockIdx.x*256 + tid;
  if (i >= NN_) return;

  u32 pth = selp[(b*2+0)*2+0], pcut = selp[(b*2+0)*2+1];
  u32 nth = selp[(b*2+1)*2+0], ncut = selp[(b*2+1)*2+1];
  u32 pv = rpv[b*NN_+i], nv = rnv[b*NN_+i];
  bool selpos = (pv > 0u) && (pv > pth || (pv == pth && (u32)i <= pcut));
  bool selneg = (nv > 0u) && (nv > nth || (nv == nth && (u32)i <= ncut));
  float cls = selpos ? 1.0f : -1.0f;
  if (selneg) cls = 0.0f;

  float tx = 0.0f, ty = 0.0f, tw = 0.0f, th = 0.0f;
  if (selpos){
    int j = midx[b*NN_+i];
    float g0=g[j][0], g1=g[j][1], g2=g[j][2], g3=g[j][3];
    int a = i % 9, cell = i / 9;
    float ax1,ay1,ax2,ay2;
    anchor_from(a, cell, ax1,ay1,ax2,ay2);
    float wgt = g2-g0, hgt = g3-g1;
    float xcg = (g2+g0)*0.5f, ycg = (g3+g1)*0.5f;
    float wr = ax2-ax1, hr = ay2-ay1;
    float xcr = (ax2+ax1)*0.5f, ycr = (ay2+ay1)*0.5f;
    float wrs = (wr > 0.0f) ? wr : 1.0f;
    float hrs = (hr > 0.0f) ? hr : 1.0f;
    tx = (wgt > 0.0f) ? (xcg - xcr)/wrs : 0.0f;
    ty = (hgt > 0.0f) ? (ycg - ycr)/hrs : 0.0f;
    tw = (wgt > 0.0f) ? logf(wgt/wrs) : 0.0f;
    th = (hgt > 0.0f) ? logf(hgt/hrs) : 0.0f;
  }
  float* o = out + (size_t)(b*NN_+i)*5;
  o[0] = cls; o[1] = tx; o[2] = ty; o[3] = tw; o[4] = th;
}

extern "C" void kernel_launch(void* const* d_in, const int* in_sizes, int n_in,
                              void* d_out, int out_size, void* d_ws, size_t ws_size,
                              hipStream_t stream) {
  const float* x = (const float*)d_in[0];
  float* out = (float*)d_out;
  char* ws = (char*)d_ws;

  // ws layout (first ZBYTES zeroed inside k_iou):
  u32* counts  = (u32*)(ws + 0);         // 128 B
  u32* listcnt = (u32*)(ws + 128);       // 128 B
  u32* hist    = (u32*)(ws + 256);       // 512 KiB  (2*16*4096*4)
  u64* bestkey = (u64*)(ws + 524544);    // 8 KiB
  u32* binfo   = (u32*)(ws + 532736);    // 128 B
  u32* selp    = (u32*)(ws + 532864);    // 256 B
  u64* list    = (u64*)(ws + 533120);    // 128 KiB (32*512*8)
  unsigned char* mcode = (unsigned char*)(ws + 664192);   // 450 KiB
  unsigned char* midx  = (unsigned char*)(ws + 1124992);  // 450 KiB
  u32* rpv = (u32*)(ws + 1585792);       // 1.76 MiB
  u32* rnv = (u32*)(ws + 3428992);       // 1.76 MiB  (end ~5.03 MiB)
  (void)ws_size; (void)in_sizes; (void)n_in; (void)out_size;

  // host-side JAX key derivation (partitionable threefry), deterministic
  Keys keys;
  for (int b = 0; b < BB_; ++b){
    u32 r0, r1;
    tf2x32(0u, 42u, 0u, (u32)b, r0, r1);
    tf2x32(r0, r1, 0u, 0u, keys.k[b][0], keys.k[b][1]);
    tf2x32(r0, r1, 0u, 1u, keys.k[b][2], keys.k[b][3]);
  }

  k_iou    <<<GRID_IOU, 256, 0, stream>>>(x, mcode, midx, bestkey, (u32*)ws);
  k_rand   <<<dim3(R0_BLKS, BB_), 256, 0, stream>>>(mcode, bestkey, keys, rpv, rnv, counts, hist);
  k_collect<<<dim3(8, BB_, 2), 256, 0, stream>>>(rpv, rnv, counts, hist, list, listcnt, binfo);
  k_decide <<<dim3(2*BB_), 64, 0, stream>>>(counts, listcnt, binfo, list, selp);
  k_out    <<<dim3(R0_BLKS, BB_), 256, 0, stream>>>(x, midx, rpv, rnv, selp, out);
}

// Round 4
// 94.044 us; speedup vs baseline: 1.7962x; 1.7962x over previous
//
#include <hip/hip_runtime.h>
#include <stdint.h>
#include <math.h>

typedef unsigned int u32;
typedef unsigned long long u64;

#define NN_ 28800
#define MM_ 64
#define BB_ 16
#define XROW_ 25
#define POS_CAP_ 128u
#define BATCH_ 256u

#define R_BLK 450                 // 28800/64 anchor-blocks per image
#define GRID_IOU (R_BLK*BB_)      // 7200 single-wave blocks

#define ZBYTES (128 + 128 + 524288)   // counts + listcnt + hist
#define ZWORDS (ZBYTES/4)             // 131136

struct Keys { u32 k[BB_][4]; };

// ---------------- threefry2x32 (JAX-exact), host+device ----------------
__host__ __device__ __forceinline__ u32 rotl32(u32 v, u32 r){ return (v<<r)|(v>>(32u-r)); }

__host__ __device__ __forceinline__ void tf2x32(u32 k0, u32 k1, u32 x0, u32 x1, u32& y0, u32& y1){
  u32 ks2 = k0 ^ k1 ^ 0x1BD11BDAu;
  x0 += k0; x1 += k1;
#define TFR(r) { x0 += x1; x1 = rotl32(x1,(r)); x1 ^= x0; }
  TFR(13) TFR(15) TFR(26) TFR(6)   x0 += k1;  x1 += ks2 + 1u;
  TFR(17) TFR(29) TFR(16) TFR(24)  x0 += ks2; x1 += k0  + 2u;
  TFR(13) TFR(15) TFR(26) TFR(6)   x0 += k0;  x1 += k1  + 3u;
  TFR(17) TFR(29) TFR(16) TFR(24)  x0 += k1;  x1 += ks2 + 4u;
  TFR(13) TFR(15) TFR(26) TFR(6)   x0 += ks2; x1 += k0  + 5u;
#undef TFR
  y0 = x0; y1 = x1;
}

// ---------------- anchors: pure-float, bit-exact vs numpy ----------------
__device__ __forceinline__ void anchor_from(int a, int cell,
                                            float& ox1, float& oy1, float& ox2, float& oy2){
  #pragma clang fp contract(off)
  int w = cell & 63;
  int h = cell >> 6;
  int p = (a >= 6) ? 2 : ((a >= 3) ? 1 : 0);
  int q = a - p*3;
  float sf = (p==0) ? 128.0f : ((p==1) ? 256.0f : 512.0f);
  const float SQH = 0.70710678118654752440f;
  const float SQ2 = 1.41421356237309514547f;
  float cw = (q==0) ? SQH : ((q==1) ? 1.0f : SQ2);
  float ch = (q==0) ? SQ2 : ((q==1) ? 1.0f : SQH);
  float hx = (sf*cw) * 0.5f;
  float hy = (sf*ch) * 0.5f;
  float cx = ((float)w + 0.5f) * 16.0f;
  float cy = ((float)h + 0.5f) * 16.0f;
  float X1 = (cx - hx) / 1024.0f;
  float Y1 = (cy - hy) / 800.0f;
  float X2 = (cx + hx) / 1024.0f;
  float Y2 = (cy + hy) / 800.0f;
  bool valid = (X1 > 0.0f) && (Y1 > 0.0f) && (X2 < 1.0f) && (Y2 < 1.0f);
  ox1 = valid ? X1 : 0.0f;
  oy1 = valid ? Y1 : 0.0f;
  ox2 = valid ? X2 : 0.0f;
  oy2 = valid ? Y2 : 0.0f;
}

// ---------------- K1: single-wave blocks; IoU once; per-gt best via LDS stash ----------------
__global__ __launch_bounds__(64) void k_iou(const float* __restrict__ x,
                                            unsigned char* __restrict__ mcode,
                                            unsigned char* __restrict__ midx,
                                            u64* __restrict__ bestkey,
                                            u32* __restrict__ zbuf){
  #pragma clang fp contract(off)
  int tid = threadIdx.x;        // 0..63, one wave
  int bid = blockIdx.x;
  { int gid = bid*64 + tid; if (gid < ZWORDS) zbuf[gid] = 0u; }

  int b   = bid / R_BLK;
  int blk = bid - b*R_BLK;
  int i0  = blk*64;
  int i   = i0 + tid;

  __shared__ float g[MM_][4];
  __shared__ float smiou[64*32];   // 8KB, rotated [anchor][(j2+anchor)&31]

  const float* gp = x + b*MM_*XROW_ + tid*XROW_ + 21;
  g[tid][0] = gp[0]; g[tid][1] = gp[1]; g[tid][2] = gp[2]; g[tid][3] = gp[3];
  __syncthreads();

  int a = i % 9, cell = i / 9;
  float ax1,ay1,ax2,ay2;
  anchor_from(a, cell, ax1,ay1,ax2,ay2);
  bool av = (ax2 > 0.0f);
  if (__ballot(av) == 0ull){
    // whole wave invalid: iou == 0 everywhere -> not pos-cand, is neg-cand
    mcode[b*NN_+i] = 2;
    midx[b*NN_+i] = 0;
    return;
  }
  float area_a = (ax2-ax1)*(ay2-ay1);
  float best = -1.0f; int bj = 0;

  for (int h = 0; h < 2; ++h){
    // ---- Phase A(h): lane = anchor, gts h*32 .. h*32+31 ----
    for (int j2 = 0; j2 < 32; ++j2){
      int j = h*32 + j2;
      float4 gg = *(const float4*)&g[j][0];
      float ix1 = fmaxf(ax1,gg.x), iy1 = fmaxf(ay1,gg.y);
      float ix2 = fminf(ax2,gg.z), iy2 = fminf(ay2,gg.w);
      float iw = fmaxf(ix2-ix1, 0.0f), ih = fmaxf(iy2-iy1, 0.0f);
      float inter = iw*ih;
      float area_g = (gg.z-gg.x)*(gg.w-gg.y);
      float den = area_a + area_g;   // exact reference op order, no FMA
      den = den - inter;
      den = den + 1e-7f;
      float iou = inter / den;
      if (iou > best){ best = iou; bj = j; }          // first-max semantics
      smiou[tid*32 + ((j2 + tid) & 31)] = iou;        // 2-way bank alias = free
    }
    __syncthreads();
    // ---- Phase B(h): lane = (gt, anchor-half); reduce 32 anchors each ----
    int gl = tid & 31;             // gt local in this half
    int ah = (tid >> 5) * 32;      // block-local anchor base for this lane
    u64 bk = 0;
    for (int t2 = 0; t2 < 32; ++t2){
      int t = ah + t2;
      u32 ib = __float_as_uint(smiou[t*32 + ((gl + t) & 31)]);
      if (ib){
        u64 key = ((u64)ib << 32) | (u64)(0xFFFFFFFFu - (u32)(i0 + t));
        if (key > bk) bk = key;
      }
    }
    // combine the two anchor-halves (lane <-> lane^32)
    u32 lo = (u32)bk, hi = (u32)(bk >> 32);
    u32 lo2 = (u32)__shfl_xor((int)lo, 32, 64);
    u32 hi2 = (u32)__shfl_xor((int)hi, 32, 64);
    u64 ob = ((u64)hi2 << 32) | (u64)lo2;
    if (ob > bk) bk = ob;
    if (tid < 32 && bk) atomicMax(&bestkey[b*MM_ + h*32 + gl], bk);
    __syncthreads();               // protect smiou before next half overwrites
  }

  unsigned char code = (unsigned char)((best > 0.7f ? 1 : 0) | (best < 0.3f ? 2 : 0));
  mcode[b*NN_+i] = code;
  midx[b*NN_+i] = (unsigned char)bj;
}

// ---------------- K2: PRNG + candidates + counts + hist ----------------
__global__ __launch_bounds__(256) void k_rand(const unsigned char* __restrict__ mcode,
                                              const u64* __restrict__ bestkey,
                                              Keys keys,
                                              u32* __restrict__ rpv, u32* __restrict__ rnv,
                                              u32* __restrict__ counts, u32* __restrict__ hist){
  int b = blockIdx.y, tid = threadIdx.x;
  int i0 = blockIdx.x*256;
  int i = i0 + tid;
  __shared__ u32 fmask[8];
  __shared__ u32 sc[2];
  if (tid < 8) fmask[tid] = 0;
  if (tid < 2) sc[tid] = 0;
  __syncthreads();
  if (tid < MM_){
    u64 key = bestkey[b*MM_ + tid];
    if ((u32)(key >> 32) != 0u){
      u32 fi = 0xFFFFFFFFu - (u32)key;
      u32 rel = fi - (u32)i0;
      if (rel < 256u) atomicOr(&fmask[rel>>5], 1u << (rel & 31));
    }
  }
  __syncthreads();
  bool pc = false, nc = false;
  if (i < NN_){
    u32 a0,a1,c0,c1;
    tf2x32(keys.k[b][0], keys.k[b][1], 0u, (u32)i, a0,a1);
    tf2x32(keys.k[b][2], keys.k[b][3], 0u, (u32)i, c0,c1);
    u32 code = mcode[b*NN_+i];
    bool fb = (fmask[tid>>5] >> (tid & 31)) & 1u;
    pc = (code & 1u) || fb;
    nc = (code >> 1) & 1u;
    u32 ph = (a0^a1) >> 9, nh = (c0^c1) >> 9;   // 23-bit rank keys
    rpv[b*NN_+i] = pc ? ph + 1u : 0u;
    rnv[b*NN_+i] = nc ? nh + 1u : 0u;
    if (pc) atomicAdd(&hist[((b*2+0)<<12) + (ph>>11)], 1u);
    if (nc) atomicAdd(&hist[((b*2+1)<<12) + (nh>>11)], 1u);
  }
  u64 bp = __ballot(pc), bn = __ballot(nc);
  if ((tid & 63) == 0){
    if (bp) atomicAdd(&sc[0], (u32)__popcll(bp));
    if (bn) atomicAdd(&sc[1], (u32)__popcll(bn));
  }
  __syncthreads();
  if (tid == 0){
    if (sc[0]) atomicAdd(&counts[b*2+0], sc[0]);
    if (sc[1]) atomicAdd(&counts[b*2+1], sc[1]);
  }
}

// ---------------- K3: threshold bin from hist + collect bin members ----------------
__global__ __launch_bounds__(256) void k_collect(const u32* __restrict__ rpv,
                                                 const u32* __restrict__ rnv,
                                                 const u32* __restrict__ counts,
                                                 const u32* __restrict__ hist,
                                                 u64* __restrict__ list,
                                                 u32* __restrict__ listcnt,
                                                 u32* __restrict__ binfo){
  int slice = blockIdx.x;        // 0..7
  int b = blockIdx.y, cls = blockIdx.z;
  int tid = threadIdx.x;
  u32 posc = counts[b*2+0], negc = counts[b*2+1];
  u32 npos = min(posc, POS_CAP_);
  u32 K   = cls ? (BATCH_ - npos) : npos;
  u32 cnt = cls ? negc : posc;
  if (cnt <= K) return;

  const u32* H = hist + ((b*2+cls) << 12);
  __shared__ u32 ts[256], ss[256];
  __shared__ u32 bc[2];
  u32 s = 0;
  #pragma unroll
  for (int q = 0; q < 16; ++q) s += H[tid*16 + q];
  ts[tid] = s; ss[tid] = s;
  __syncthreads();
  for (int off = 1; off < 256; off <<= 1){
    u32 vv = (tid + off < 256) ? ss[tid + off] : 0u;
    __syncthreads();
    ss[tid] += vv;
    __syncthreads();
  }
  u32 excl = (tid < 255) ? ss[tid+1] : 0u;
  if (excl < K && excl + ts[tid] >= K){
    u32 acc = excl;
    for (int q = 15; q >= 0; --q){
      u32 h = H[tid*16 + q];
      if (acc + h >= K){ bc[0] = (u32)(tid*16 + q); bc[1] = K - acc; break; }
      acc += h;
    }
  }
  __syncthreads();
  u32 B = bc[0];
  if (slice == 0 && tid == 0) binfo[b*2+cls] = bc[1];   // Kp

  const u32* v = (cls ? rnv : rpv) + (size_t)b*NN_;
  int ibase = slice * 3600;
  for (int i = ibase + tid; i < ibase + 3600; i += 256){
    u32 xv = v[i];
    if (xv && ((xv - 1u) >> 11) == B){
      u32 p = atomicAdd(&listcnt[b*2+cls], 1u);
      if (p < 512u) list[(size_t)(b*2+cls)*512 + p] = ((u64)xv << 32) | (u32)i;
    }
  }
}

// ---------------- K4: exact (vstar, cut) from the tiny bin list ----------------
__global__ __launch_bounds__(64) void k_decide(const u32* __restrict__ counts,
                                               const u32* __restrict__ listcnt,
                                               const u32* __restrict__ binfo,
                                               const u64* __restrict__ list,
                                               u32* __restrict__ selp){
  int id = blockIdx.x;
  int b = id >> 1, cls = id & 1;
  int lane = threadIdx.x;
  u32 posc = counts[b*2+0], negc = counts[b*2+1];
  u32 npos = min(posc, POS_CAP_);
  u32 K   = cls ? (BATCH_ - npos) : npos;
  u32 cnt = cls ? negc : posc;
  if (cnt <= K){
    if (lane == 0){ selp[id*2+0] = 0u; selp[id*2+1] = 0xFFFFFFFFu; }
    return;
  }
  u32 Kp = binfo[id];
  u32 n = min(listcnt[id], 512u);
  __shared__ u64 L[512];
  for (u32 e = lane; e < n; e += 64) L[e] = list[(size_t)id*512 + e];
  __syncthreads();
  for (u32 e = lane; e < n; e += 64){
    u64 me = L[e]; u32 mv = (u32)(me >> 32), mi = (u32)me;
    u32 r = 0;
    for (u32 t = 0; t < n; ++t){
      u64 o = L[t]; u32 ov = (u32)(o >> 32), oi = (u32)o;
      r += (ov > mv) || (ov == mv && oi < mi);
    }
    if (r == Kp - 1u){ selp[id*2+0] = mv; selp[id*2+1] = mi; }
  }
}

// ---------------- K5: final cls + encoded offsets ----------------
__global__ __launch_bounds__(256) void k_out(const float* __restrict__ x,
                                             const unsigned char* __restrict__ midx,
                                             const u32* __restrict__ rpv,
                                             const u32* __restrict__ rnv,
                                             const u32* __restrict__ selp,
                                             float* __restrict__ out){
  #pragma clang fp contract(off)
  int b = blockIdx.y, tid = threadIdx.x;
  __shared__ float g[MM_][4];
  g[tid>>2][tid&3] = x[b*MM_*XROW_ + (tid>>2)*XROW_ + 21 + (tid&3)];
  __syncthreads();
  int i = blockIdx.x*256 + tid;
  if (i >= NN_) return;

  u32 pth = selp[(b*2+0)*2+0], pcut = selp[(b*2+0)*2+1];
  u32 nth = selp[(b*2+1)*2+0], ncut = selp[(b*2+1)*2+1];
  u32 pv = rpv[b*NN_+i], nv = rnv[b*NN_+i];
  bool selpos = (pv > 0u) && (pv > pth || (pv == pth && (u32)i <= pcut));
  bool selneg = (nv > 0u) && (nv > nth || (nv == nth && (u32)i <= ncut));
  float cls = selpos ? 1.0f : -1.0f;
  if (selneg) cls = 0.0f;

  float tx = 0.0f, ty = 0.0f, tw = 0.0f, th = 0.0f;
  if (selpos){
    int j = midx[b*NN_+i];
    float g0=g[j][0], g1=g[j][1], g2=g[j][2], g3=g[j][3];
    int a = i % 9, cell = i / 9;
    float ax1,ay1,ax2,ay2;
    anchor_from(a, cell, ax1,ay1,ax2,ay2);
    float wgt = g2-g0, hgt = g3-g1;
    float xcg = (g2+g0)*0.5f, ycg = (g3+g1)*0.5f;
    float wr = ax2-ax1, hr = ay2-ay1;
    float xcr = (ax2+ax1)*0.5f, ycr = (ay2+ay1)*0.5f;
    float wrs = (wr > 0.0f) ? wr : 1.0f;
    float hrs = (hr > 0.0f) ? hr : 1.0f;
    tx = (wgt > 0.0f) ? (xcg - xcr)/wrs : 0.0f;
    ty = (hgt > 0.0f) ? (ycg - ycr)/hrs : 0.0f;
    tw = (wgt > 0.0f) ? logf(wgt/wrs) : 0.0f;
    th = (hgt > 0.0f) ? logf(hgt/hrs) : 0.0f;
  }
  float* o = out + (size_t)(b*NN_+i)*5;
  o[0] = cls; o[1] = tx; o[2] = ty; o[3] = tw; o[4] = th;
}

extern "C" void kernel_launch(void* const* d_in, const int* in_sizes, int n_in,
                              void* d_out, int out_size, void* d_ws, size_t ws_size,
                              hipStream_t stream) {
  const float* x = (const float*)d_in[0];
  float* out = (float*)d_out;
  char* ws = (char*)d_ws;

  // ws layout (first ZBYTES zeroed inside k_iou; bestkey zeroed by memset):
  u32* counts  = (u32*)(ws + 0);         // 128 B
  u32* listcnt = (u32*)(ws + 128);       // 128 B
  u32* hist    = (u32*)(ws + 256);       // 512 KiB
  u64* bestkey = (u64*)(ws + 524544);    // 8 KiB
  u32* binfo   = (u32*)(ws + 532736);    // 128 B
  u32* selp    = (u32*)(ws + 532864);    // 256 B
  u64* list    = (u64*)(ws + 533120);    // 128 KiB
  unsigned char* mcode = (unsigned char*)(ws + 664192);
  unsigned char* midx  = (unsigned char*)(ws + 1124992);
  u32* rpv = (u32*)(ws + 1585792);
  u32* rnv = (u32*)(ws + 3428992);
  (void)ws_size; (void)in_sizes; (void)n_in; (void)out_size;

  Keys keys;
  for (int b = 0; b < BB_; ++b){
    u32 r0, r1;
    tf2x32(0u, 42u, 0u, (u32)b, r0, r1);
    tf2x32(r0, r1, 0u, 0u, keys.k[b][0], keys.k[b][1]);
    tf2x32(r0, r1, 0u, 1u, keys.k[b][2], keys.k[b][3]);
  }

  hipMemsetAsync(bestkey, 0, 8192, stream);
  k_iou    <<<GRID_IOU, 64, 0, stream>>>(x, mcode, midx, bestkey, (u32*)ws);
  k_rand   <<<dim3(113, BB_), 256, 0, stream>>>(mcode, bestkey, keys, rpv, rnv, counts, hist);
  k_collect<<<dim3(8, BB_, 2), 256, 0, stream>>>(rpv, rnv, counts, hist, list, listcnt, binfo);
  k_decide <<<dim3(2*BB_), 64, 0, stream>>>(counts, listcnt, binfo, list, selp);
  k_out    <<<dim3(113, BB_), 256, 0, stream>>>(x, midx, rpv, rnv, selp, out);
}